// Round 6
// baseline (81.444 us; speedup 1.0000x reference)
//
#include <hip/hip_runtime.h>

#define B_  32
#define T_  4096
#define D_  256
#define D4_ 64          // D_/4 float4 columns

typedef float f32x4 __attribute__((ext_vector_type(4)));

__device__ __forceinline__ f32x4 sigmoid4(f32x4 v) {
    f32x4 r;
    r[0] = 1.0f / (1.0f + expf(-v[0]));
    r[1] = 1.0f / (1.0f + expf(-v[1]));
    r[2] = 1.0f / (1.0f + expf(-v[2]));
    r[3] = 1.0f / (1.0f + expf(-v[3]));
    return r;
}

// K1: per-chunk local scan with zero init (exact x0 for chunk 0),
// writes chunk-end aggregate E[b][c][d4]. One chunk per wave.
__global__ __launch_bounds__(256) void ema_carry(
    const f32x4* __restrict__ x, const f32x4* __restrict__ la,
    f32x4* __restrict__ E, int NC, int L) {
    const int wid  = threadIdx.x >> 6;
    const int lane = threadIdx.x & 63;
    const int g = blockIdx.x * 4 + wid;        // chunk-task id in [0, B_*NC)
    const int b = g / NC;
    const int c = g % NC;

    const f32x4 al = sigmoid4(la[lane]);
    const f32x4 om = 1.0f - al;

    size_t idx = ((size_t)b * T_ + (size_t)c * L) * D4_ + lane;
    f32x4 y = 0.0f;
    int i0 = 0;
    if (c == 0) {                               // y_0 = x_0 exactly
        y = x[idx];
        idx += D4_;
        i0 = 1;
    }
    #pragma unroll 8
    for (int i = i0; i < L; ++i) {
        y = al * y + om * x[idx];
        idx += D4_;
    }
    E[(size_t)g * D4_ + lane] = y;
}

// K1.5: per row b, compute incoming-state H[b][c] for every chunk.
// S_c = aL*S_{c-1} + E_c (S_{-1}=0), H_c = S_{c-1}.
// 4 segments of NC/4 chunks scanned in parallel, combined via LDS.
__global__ __launch_bounds__(256) void ema_escan(
    const f32x4* __restrict__ la, const f32x4* __restrict__ E,
    f32x4* __restrict__ H, int NC, int log2L) {
    __shared__ f32x4 s_A[4][64];

    const int b    = blockIdx.x;
    const int lane = threadIdx.x & 63;
    const int seg  = threadIdx.x >> 6;          // 0..3
    const int NCS  = NC >> 2;                   // chunks per segment
    const int c0   = seg * NCS;

    const f32x4 al = sigmoid4(la[lane]);
    f32x4 aL = al;                              // al^L
    for (int k = 0; k < log2L; ++k) aL = aL * aL;

    const f32x4* Eb = E + (size_t)b * NC * D4_;
    f32x4* Hb       = H + (size_t)b * NC * D4_;

    // pass 1: segment aggregate A_seg (zero-init scan over the segment)
    f32x4 s = 0.0f;
    for (int i = 0; i < NCS; ++i)
        s = aL * s + Eb[(size_t)(c0 + i) * D4_ + lane];
    s_A[seg][lane] = s;
    __syncthreads();

    // exclusive prefix across segments: X_seg
    f32x4 X = 0.0f;
    #pragma unroll
    for (int j = 0; j < 3; ++j)
        if (j < seg) X = /* aL^NCS * X */ s_A[j][lane] + [&]{
            f32x4 t = X;
            return t; }() * 0.0f;               // placeholder, replaced below
    // (rewritten without lambda below)
    X = 0.0f;
    {
        f32x4 aLn = aL;                         // aL^NCS via squarings of aL
        int n = NCS;                            // NCS is a power of two
        int lg = 0; while ((1 << lg) < n) ++lg;
        f32x4 m = aL;
        for (int k = 0; k < lg; ++k) m = m * m; // m = aL^NCS
        (void)aLn;
        #pragma unroll
        for (int j = 0; j < 3; ++j)
            if (j < seg) X = m * X + s_A[j][lane];
    }

    // pass 2: H_c = incoming state; h starts at X_seg
    f32x4 h = X;
    for (int i = 0; i < NCS; ++i) {
        size_t o = (size_t)(c0 + i) * D4_ + lane;
        Hb[o] = h;
        h = aL * h + Eb[o];
    }
}

// K2: pure streaming rescan: load H, scan chunk from x (L3-hot), NT-store y.
__global__ __launch_bounds__(256) void ema_apply(
    const f32x4* __restrict__ x, const f32x4* __restrict__ la,
    const f32x4* __restrict__ H, f32x4* __restrict__ yout,
    int NC, int L) {
    const int wid  = threadIdx.x >> 6;
    const int lane = threadIdx.x & 63;
    const int g = blockIdx.x * 4 + wid;
    const int b = g / NC;
    const int c = g % NC;

    const f32x4 al = sigmoid4(la[lane]);
    const f32x4 om = 1.0f - al;

    size_t idx = ((size_t)b * T_ + (size_t)c * L) * D4_ + lane;
    f32x4 acc = H[(size_t)g * D4_ + lane];
    int i0 = 0;
    if (c == 0) {
        acc = x[idx];                           // y_0 = x_0
        __builtin_nontemporal_store(acc, &yout[idx]);
        idx += D4_;
        i0 = 1;
    }
    #pragma unroll 8
    for (int i = i0; i < L; ++i) {
        acc = al * acc + om * x[idx];
        __builtin_nontemporal_store(acc, &yout[idx]);
        idx += D4_;
    }
}

extern "C" void kernel_launch(void* const* d_in, const int* in_sizes, int n_in,
                              void* d_out, int out_size, void* d_ws, size_t ws_size,
                              hipStream_t stream) {
    const f32x4* x  = (const f32x4*)d_in[0];
    const f32x4* la = (const f32x4*)d_in[1];
    f32x4* out = (f32x4*)d_out;

    // E and H each need B_*NC*D_ floats in d_ws.
    int NC = 128;
    while (NC > 4 && 2 * (size_t)B_ * NC * D_ * sizeof(float) > ws_size) NC >>= 1;
    const int L = T_ / NC;
    int log2L = 0;
    while ((1 << log2L) < L) ++log2L;

    f32x4* E = (f32x4*)d_ws;
    f32x4* H = E + (size_t)B_ * NC * D4_;
    const int ntasks = B_ * NC;                 // 4 chunk-tasks per block
    dim3 blk(256);
    dim3 grd(ntasks / 4);

    ema_carry<<<grd, blk, 0, stream>>>(x, la, E, NC, L);
    ema_escan<<<B_, blk, 0, stream>>>(la, E, H, NC, log2L);
    ema_apply<<<grd, blk, 0, stream>>>(x, la, H, out, NC, L);
}

// Round 7
// 74.803 us; speedup vs baseline: 1.0888x; 1.0888x over previous
//
#include <hip/hip_runtime.h>

#define B_  32
#define T_  4096
#define D_  256
#define D4_ 64          // D_/4 float4 columns

typedef float f32x4 __attribute__((ext_vector_type(4)));

__device__ __forceinline__ f32x4 sigmoid4(f32x4 v) {
    f32x4 r;
    r[0] = 1.0f / (1.0f + expf(-v[0]));
    r[1] = 1.0f / (1.0f + expf(-v[1]));
    r[2] = 1.0f / (1.0f + expf(-v[2]));
    r[3] = 1.0f / (1.0f + expf(-v[3]));
    return r;
}

// K1: per-chunk local scan with zero init (exact x0 for chunk 0),
// writes chunk-end aggregate E[b][c][d4]. One chunk per wave.
__global__ __launch_bounds__(256) void ema_carry(
    const f32x4* __restrict__ x, const f32x4* __restrict__ la,
    f32x4* __restrict__ E, int NC, int L) {
    const int wid  = threadIdx.x >> 6;
    const int lane = threadIdx.x & 63;
    const int g = blockIdx.x * 4 + wid;        // chunk-task id in [0, B_*NC)
    const int b = g / NC;
    const int c = g % NC;

    const f32x4 al = sigmoid4(la[lane]);
    const f32x4 om = 1.0f - al;

    size_t idx = ((size_t)b * T_ + (size_t)c * L) * D4_ + lane;
    f32x4 y = 0.0f;
    int i0 = 0;
    if (c == 0) {                               // y_0 = x_0 exactly
        y = x[idx];
        idx += D4_;
        i0 = 1;
    }
    #pragma unroll 8
    for (int i = i0; i < L; ++i) {
        y = al * y + om * x[idx];
        idx += D4_;
    }
    E[(size_t)g * D4_ + lane] = y;
}

// K2: fold predecessor aggregates in-register (8-wide batched loads),
// then rescan the chunk from x (L3-hot) and write y with NT stores.
__global__ __launch_bounds__(256) void ema_apply(
    const f32x4* __restrict__ x, const f32x4* __restrict__ la,
    const f32x4* __restrict__ E, f32x4* __restrict__ yout,
    int NC, int L, int log2L) {
    const int wid  = threadIdx.x >> 6;
    const int lane = threadIdx.x & 63;
    const int g = blockIdx.x * 4 + wid;
    const int b = g / NC;
    const int c = g % NC;

    const f32x4 al = sigmoid4(la[lane]);
    const f32x4 om = 1.0f - al;

    f32x4 aL = al;                              // al^L via log2L squarings
    for (int k = 0; k < log2L; ++k) aL = aL * aL;
    const f32x4 aL2 = aL * aL;
    const f32x4 aL4 = aL2 * aL2;
    const f32x4 aL8 = aL4 * aL4;

    // H = incoming state for chunk c = sum_{j<c} aL^(c-1-j) * E[b][j]
    const f32x4* Eb = E + ((size_t)b * NC) * D4_ + lane;
    f32x4 H = 0.0f;
    int j = 0;
    for (; j + 8 <= c; j += 8) {                // 8 independent loads per round
        f32x4 e0 = Eb[(size_t)(j + 0) * D4_];
        f32x4 e1 = Eb[(size_t)(j + 1) * D4_];
        f32x4 e2 = Eb[(size_t)(j + 2) * D4_];
        f32x4 e3 = Eb[(size_t)(j + 3) * D4_];
        f32x4 e4 = Eb[(size_t)(j + 4) * D4_];
        f32x4 e5 = Eb[(size_t)(j + 5) * D4_];
        f32x4 e6 = Eb[(size_t)(j + 6) * D4_];
        f32x4 e7 = Eb[(size_t)(j + 7) * D4_];
        f32x4 t = e0;
        t = t * aL + e1;
        t = t * aL + e2;
        t = t * aL + e3;
        t = t * aL + e4;
        t = t * aL + e5;
        t = t * aL + e6;
        t = t * aL + e7;
        H = aL8 * H + t;
    }
    for (; j < c; ++j)
        H = aL * H + Eb[(size_t)j * D4_];

    // rescan chunk from incoming state H
    size_t idx = ((size_t)b * T_ + (size_t)c * L) * D4_ + lane;
    f32x4 acc = H;
    int i0 = 0;
    if (c == 0) {
        acc = x[idx];                           // y_0 = x_0
        __builtin_nontemporal_store(acc, &yout[idx]);
        idx += D4_;
        i0 = 1;
    }
    #pragma unroll 8
    for (int i = i0; i < L; ++i) {
        acc = al * acc + om * x[idx];
        __builtin_nontemporal_store(acc, &yout[idx]);
        idx += D4_;
    }
}

extern "C" void kernel_launch(void* const* d_in, const int* in_sizes, int n_in,
                              void* d_out, int out_size, void* d_ws, size_t ws_size,
                              hipStream_t stream) {
    const f32x4* x  = (const f32x4*)d_in[0];
    const f32x4* la = (const f32x4*)d_in[1];
    f32x4* out = (f32x4*)d_out;

    // E needs B_*NC*D_ floats in d_ws.
    int NC = 128;                               // 1024 blocks, 16 waves/CU
    while (NC > 1 && (size_t)B_ * NC * D_ * sizeof(float) > ws_size) NC >>= 1;
    const int L = T_ / NC;
    int log2L = 0;
    while ((1 << log2L) < L) ++log2L;

    f32x4* E = (f32x4*)d_ws;
    const int ntasks = B_ * NC;                 // 4 chunk-tasks per block
    dim3 blk(256);
    dim3 grd(ntasks / 4);

    ema_carry<<<grd, blk, 0, stream>>>(x, la, E, NC, L);
    ema_apply<<<grd, blk, 0, stream>>>(x, la, E, out, NC, L, log2L);
}